// Round 14
// baseline (81.329 us; speedup 1.0000x reference)
//
#include <hip/hip_runtime.h>

#define BATCH 512
#define DIM   256
#define UNITS 256

typedef __bf16 bf16x8 __attribute__((ext_vector_type(8)));
typedef float  f32x4  __attribute__((ext_vector_type(4)));

__device__ __forceinline__ bf16x8 ld_bf8(const unsigned short* p) {
    uint4 u = *reinterpret_cast<const uint4*>(p);
    return __builtin_bit_cast(bf16x8, u);
}

__device__ __forceinline__ unsigned short bfc(float f) {
    return __builtin_bit_cast(unsigned short, (__bf16)f);
}

__device__ __forceinline__ bf16x8 cvt8(float4 a, float4 b) {
    bf16x8 r;
    r[0] = (__bf16)a.x; r[1] = (__bf16)a.y; r[2] = (__bf16)a.z; r[3] = (__bf16)a.w;
    r[4] = (__bf16)b.x; r[5] = (__bf16)b.y; r[6] = (__bf16)b.z; r[7] = (__bf16)b.w;
    return r;
}

// async 16B global -> LDS (linear dest: wave-uniform base + lane*16)
__device__ __forceinline__ void gload16(void* lds, const void* g) {
    __builtin_amdgcn_global_load_lds(
        (const __attribute__((address_space(1))) unsigned int*)g,
        (__attribute__((address_space(3))) unsigned int*)lds, 16, 0, 0);
}

// Prep: mu_out (f32), s_b = x.x + tr(Sigma_b), softplus table,
//       Wt2 fragment-linear: Wt2[((u>>4)*8+kk)*512 + lane*8 + e] = bf16(W[k][u]),
//       lane = lq*16 + (u&15), k = kk*32 + lq*8 + e.
__global__ __launch_bounds__(256) void prep_kernel(
    const float* __restrict__ mu_in, const float* __restrict__ Sigma,
    const float* __restrict__ W, const float* __restrict__ w_sigma,
    float* __restrict__ mu_out, unsigned short* __restrict__ Wt2,
    float* __restrict__ sb, float* __restrict__ sp)
{
    const int b = blockIdx.x;
    const int t = threadIdx.x;

    __shared__ float mrow[DIM];
    mrow[t] = mu_in[b * DIM + t];
    __syncthreads();

    float acc = 0.f;
#pragma unroll 8
    for (int d = 0; d < DIM; ++d) acc += mrow[d] * W[d * UNITS + t];
    mu_out[b * UNITS + t] = acc;

    float xv  = mrow[t];
    float val = xv * xv + Sigma[(size_t)b * DIM * DIM + (size_t)t * (DIM + 1)];
#pragma unroll
    for (int o = 32; o > 0; o >>= 1) val += __shfl_down(val, o);
    __shared__ float wsum[4];
    if ((t & 63) == 0) wsum[t >> 6] = val;
    __syncthreads();
    if (t == 0) sb[b] = wsum[0] + wsum[1] + wsum[2] + wsum[3];

    if (b < UNITS) {
        const int u   = b;
        const int idx = ((u >> 4) * 8 + (t >> 5)) * 512 + ((t >> 3) & 3) * 128
                      + (u & 15) * 8 + (t & 7);
        Wt2[idx] = bfc(W[t * UNITS + u]);
    }
    if (b == 0) sp[t] = log1pf(expf(w_sigma[t]));
}

// Main: ONE block per batch, 1024 threads = 16 waves (wave w owns 16 rows).
// R10's geometry + R9/R13's full-drain discipline (__syncthreads per iter,
// NO counted vmcnt) + R13's swapped-operand coalesced epilogue.
//   Per CU: 2 sequential blocks x 10 drains (vs R13's 4 x 10).
__global__ __launch_bounds__(1024, 4) void sigma_kernel(
    const float* __restrict__ Sigma, const unsigned short* __restrict__ Wt2,
    const float* __restrict__ sb, const float* __restrict__ sp,
    float* __restrict__ out)
{
    // [0,65536):      Sigma f32 k-tile double buffer (32 KB each)
    // [65536,98304):  Wt2 slab double buffer (16 KB each)
    // Pt bf16 [256 v][512 B] XOR-chunk-swizzled: unions [0,131072) after
    __shared__ __align__(1024) char smem[131072];
    char* slab = smem + 65536;

    const int b    = blockIdx.x;
    const int tid  = threadIdx.x;
    const int lane = tid & 63;
    const int w    = tid >> 6;     // 0..15
    const int lq   = lane >> 4;    // 0..3
    const int lr   = lane & 15;    // 0..15

    const float* S = Sigma + (size_t)b * DIM * DIM;
    float*       O = out   + (size_t)b * UNITS * UNITS;
    const float  sbv = sb[b];

    // Sigma staging: wave w stages rows [16w,16w+16) (2 gload16 per tile).
    // lane l -> row +srw (srw = l>>3), src chunk (l&7)^srw (XOR involution).
    const int srw  = lane >> 3;
    const int csrc = ((lane & 7) ^ srw) * 16;
    const char* gS0 = (const char*)S + (size_t)(16 * w + srw) * 1024 + csrc;
    const char* gS1 = gS0 + 8 * 1024;
    const int   ldsw = w * 2048;

    // Wt2 slab: wave w stages fragment j=w (1 KB per k-iter);
    // same base serves stage 2's A-frags (u-group w).
    const unsigned short* wfrag = Wt2 + (size_t)w * 8 * 512 + lane * 8;

    // stage-1 A-frag read: row 16w+lr (wave-private), same XOR on read
    const int arow = (16 * w + lr) * 128;
    const int h7   = lr & 7;
    const int c0   = ((2 * lq + 0) ^ h7) * 16;
    const int c1   = ((2 * lq + 1) ^ h7) * 16;

    f32x4 acc[16];
#pragma unroll
    for (int j = 0; j < 16; ++j)
#pragma unroll
        for (int r = 0; r < 4; ++r) acc[j][r] = 0.f;

    // ---- prologue: stage tile 0 + slab 0; single drain ----
    gload16(smem + ldsw, gS0);
    gload16(smem + ldsw + 1024, gS1);
    gload16(slab + w * 1024, wfrag);
    __syncthreads();

    // ---- Stage 1: P[d][v] = sum_e Sigma[d][e] * W[e][v] ----
#pragma unroll
    for (int kk = 0; kk < 8; ++kk) {
        const int cur  = (kk & 1) * 32768;
        const char* sl = slab + (kk & 1) * 16384;

        // prefetch tile kk+1 (drained by this iter's end barrier)
        if (kk < 7) {
            const int nxt = cur ^ 32768;
            gload16(smem + nxt + ldsw, gS0 + (kk + 1) * 128);
            gload16(smem + nxt + ldsw + 1024, gS1 + (kk + 1) * 128);
            gload16(slab + ((kk + 1) & 1) * 16384 + w * 1024,
                    wfrag + (kk + 1) * 512);
        }

        // A-frag: wave-private Sigma row (XOR-swizzled chunks)
        float4 fa0 = *reinterpret_cast<const float4*>(smem + cur + arow + c0);
        float4 fa1 = *reinterpret_cast<const float4*>(smem + cur + arow + c1);
        bf16x8 af  = cvt8(fa0, fa1);

        // B-frags: shared slab (16 frags x 1 KB, contiguous lane*16)
#pragma unroll
        for (int j = 0; j < 16; ++j) {
            bf16x8 bf = *reinterpret_cast<const bf16x8*>(sl + j * 1024 + lane * 16);
            acc[j] = __builtin_amdgcn_mfma_f32_16x16x32_bf16(af, bf, acc[j], 0, 0, 0);
        }

        __syncthreads();   // drains prefetch + protects buffer reuse
    }

    // ---- write P^T into LDS: Pt[v][d], 16B chunk index ^= (v&7) ----
    // acc[j][r] = P[d = 16w + 4lq + r][v = 16j + lr]
    {
        const int chb = 2 * w + (lq >> 1);
        const int sub = 8 * (lq & 1);
#pragma unroll
        for (int j = 0; j < 16; ++j) {
            const int v = 16 * j + lr;
            uint2 pk;
            pk.x = (unsigned)bfc(acc[j][0]) | ((unsigned)bfc(acc[j][1]) << 16);
            pk.y = (unsigned)bfc(acc[j][2]) | ((unsigned)bfc(acc[j][3]) << 16);
            *reinterpret_cast<uint2*>(smem + v * 512 + ((chb ^ (v & 7)) * 16) + sub) = pk;
        }
    }
    __syncthreads();

    // ---- Stage 2: out[u][v] = sum_d W[d][u] * P[d][v], SWAPPED operands:
    // A = Pt frag (v rows), B = W frag (u cols) -> D[v][u]: 4 consecutive v
    // at fixed u = 16w + lr -> coalesced f32x4 stores.
#pragma unroll
    for (int j = 0; j < 16; ++j)
#pragma unroll
        for (int r = 0; r < 4; ++r) acc[j][r] = 0.f;

#pragma unroll
    for (int kk = 0; kk < 8; ++kk) {
        bf16x8 af = ld_bf8(wfrag + kk * 512);   // frag (u16=w, kk), L2-hot
#pragma unroll
        for (int j = 0; j < 16; ++j) {
            const int v  = 16 * j + lr;
            const int ch = (4 * kk + lq) ^ (v & 7);
            bf16x8 pb = *reinterpret_cast<const bf16x8*>(smem + v * 512 + ch * 16);
            acc[j] = __builtin_amdgcn_mfma_f32_16x16x32_bf16(pb, af, acc[j], 0, 0, 0);
        }
    }

    // ---- Epilogue: u = 16w + lr; v = 16j + 4lq + r; vectorized stores ----
    {
        const int u = 16 * w + lr;
#pragma unroll
        for (int j = 0; j < 16; ++j) {
            const int vb = 16 * j + 4 * lq;
            f32x4 val = acc[j];
            f32x4 spv = *reinterpret_cast<const f32x4*>(&sp[vb]);
#pragma unroll
            for (int r = 0; r < 4; ++r) {
                float x = val[r];
                if (u == vb + r) x += sbv * spv[r];
                x = __builtin_isfinite(x) ? x : 0.0f;
                if (u == vb + r) x = fabsf(x);
                val[r] = x;
            }
            *reinterpret_cast<f32x4*>(&O[(size_t)u * UNITS + vb]) = val;
        }
    }
}

extern "C" void kernel_launch(void* const* d_in, const int* in_sizes, int n_in,
                              void* d_out, int out_size, void* d_ws, size_t ws_size,
                              hipStream_t stream) {
    const float* mu_in  = (const float*)d_in[0];
    const float* Sigma  = (const float*)d_in[1];
    const float* w_mu   = (const float*)d_in[2];
    const float* w_sig  = (const float*)d_in[3];

    float* mu_out  = (float*)d_out;
    float* Sig_out = (float*)d_out + BATCH * UNITS;

    unsigned short* Wt2 = (unsigned short*)d_ws;                      // 131072 B
    float* sb = (float*)((char*)d_ws + (size_t)DIM * UNITS * 2);      // 512 f32
    float* sp = sb + BATCH;                                           // 256 f32

    prep_kernel<<<BATCH, 256, 0, stream>>>(mu_in, Sigma, w_mu, w_sig, mu_out, Wt2, sb, sp);
    sigma_kernel<<<BATCH, 1024, 0, stream>>>(Sigma, Wt2, sb, sp, Sig_out);
}